// Round 13
// baseline (1256.079 us; speedup 1.0000x reference)
//
#include <hip/hip_runtime.h>
#include <stdint.h>

#define NB 16
#define NL 100
#define NOUT (16*101*101)

typedef _Float16 f16x8 __attribute__((ext_vector_type(8)));
typedef float f32x4 __attribute__((ext_vector_type(4)));

__device__ __forceinline__ float sigm(float x) {
    x = fminf(fmaxf(x, -30.f), 30.f);
    return 1.f / (1.f + __expf(-x));
}
__device__ __forceinline__ float tanh_(float x) {
    x = fminf(fmaxf(x, -15.f), 15.f);
    float t = __expf(2.f * x);
    return (t - 1.f) / (t + 1.f);
}
__device__ __forceinline__ uint32_t pack2h(_Float16 a, _Float16 b) {
    return (uint32_t)__builtin_bit_cast(uint16_t, a) |
           ((uint32_t)__builtin_bit_cast(uint16_t, b) << 16);
}
#define MFMA16(A, B, C) __builtin_amdgcn_mfma_f32_16x16x32_f16( \
    __builtin_bit_cast(f16x8, A), (B), (C), 0, 0, 0)

// ---------------- fused pack kernel ----------------
// segments: [0,262144) whh | [262144,786432) wih | [786432,802816) w2
//           [802816,811008) bias | [811008,1067008) x0
__global__ __launch_bounds__(256) void pack_all(const float* __restrict__ w_hh0,
                                                const float* __restrict__ w_hh,
                                                const float* __restrict__ w_ih0,
                                                const float* __restrict__ w_ih,
                                                const float* __restrict__ W2,
                                                const float* __restrict__ b_ih0,
                                                const float* __restrict__ b_hh0,
                                                const float* __restrict__ b_ih,
                                                const float* __restrict__ b_hh,
                                                const float* __restrict__ we,
                                                const int* __restrict__ pos_idx,
                                                const float* __restrict__ pos_emb,
                                                uint32_t* __restrict__ whhpk,
                                                uint32_t* __restrict__ wihpk,
                                                uint32_t* __restrict__ w2pk,
                                                float* __restrict__ biasp,
                                                _Float16* __restrict__ xhi,
                                                _Float16* __restrict__ xlo) {
    int gid = blockIdx.x * 256 + threadIdx.x;
    if (gid < 262144) {
        int idx = gid;
        int l6 = idx & 63;
        int kc = (idx >> 6) & 7;
        int mt = (idx >> 9) & 63;
        int ld = idx >> 15;
        int layer = ld >> 1, d = ld & 1;
        int row = mt * 16 + (l6 & 15);
        int k0 = kc * 32 + (l6 >> 4) * 8;
        const float* src = (layer == 0)
            ? &w_hh0[((size_t)d * 1024 + row) * 256]
            : &w_hh[(((size_t)(layer - 1) * 2 + d) * 1024 + row) * 256];
        uint4 o;
        o.x = pack2h((_Float16)src[k0 + 0], (_Float16)src[k0 + 1]);
        o.y = pack2h((_Float16)src[k0 + 2], (_Float16)src[k0 + 3]);
        o.z = pack2h((_Float16)src[k0 + 4], (_Float16)src[k0 + 5]);
        o.w = pack2h((_Float16)src[k0 + 6], (_Float16)src[k0 + 7]);
        *(uint4*)&whhpk[(size_t)idx * 4] = o;
    } else if (gid < 786432) {
        int idx = gid - 262144;
        int l6 = idx & 63;
        int kc = (idx >> 6) & 15;
        int mt = (idx >> 10) & 63;
        int dl = idx >> 16;
        int row = mt * 16 + (l6 & 15);
        int k0 = kc * 32 + (l6 >> 4) * 8;
        float v[8];
#pragma unroll
        for (int j = 0; j < 8; ++j) {
            int k = k0 + j;
            if (dl < 2) v[j] = (k < 150) ? w_ih0[((size_t)dl * 1024 + row) * 150 + k] : 0.f;
            else        v[j] = w_ih[((size_t)(dl - 2) * 1024 + row) * 512 + k];
        }
        uint4 o;
        o.x = pack2h((_Float16)v[0], (_Float16)v[1]);
        o.y = pack2h((_Float16)v[2], (_Float16)v[3]);
        o.z = pack2h((_Float16)v[4], (_Float16)v[5]);
        o.w = pack2h((_Float16)v[6], (_Float16)v[7]);
        *(uint4*)&wihpk[(size_t)idx * 4] = o;
    } else if (gid < 802816) {
        int idx = gid - 786432;
        int l6 = idx & 63;
        int nt = (idx >> 6) & 7;
        int sp = (idx >> 9) & 1;
        int kc = idx >> 10;
        int ch = nt * 16 + (l6 & 15);
        int k0 = kc * 32 + (l6 >> 4) * 8;
        uint32_t dw[4];
#pragma unroll
        for (int dwi = 0; dwi < 4; ++dwi) {
            float x0 = W2[(size_t)ch * 512 + k0 + dwi * 2 + 0];
            float x1 = W2[(size_t)ch * 512 + k0 + dwi * 2 + 1];
            _Float16 h0 = (_Float16)x0, h1 = (_Float16)x1;
            _Float16 v0 = sp ? (_Float16)(x0 - (float)h0) : h0;
            _Float16 v1 = sp ? (_Float16)(x1 - (float)h1) : h1;
            dw[dwi] = pack2h(v0, v1);
        }
        *(uint4*)&w2pk[(size_t)idx * 4] = make_uint4(dw[0], dw[1], dw[2], dw[3]);
    } else if (gid < 811008) {
        int idx = gid - 802816;
        int g = idx & 1023;
        int ld = idx >> 10;
        int l = ld >> 1, d = ld & 1;
        float v;
        if (l == 0) v = b_ih0[d * 1024 + g] + b_hh0[d * 1024 + g];
        else {
            size_t o = ((size_t)(l - 1) * 2 + d) * 1024 + g;
            v = b_ih[o] + b_hh[o];
        }
        biasp[idx] = v;
    } else if (gid < 1067008) {
        int idx = gid - 811008;
        int mp = idx / 160, k = idx % 160;
        int tt = mp >> 4, b = mp & 15;
        float v;
        if (k < 100) v = we[((size_t)b * 100 + tt) * 100 + k];
        else if (k < 150) v = pos_emb[(size_t)pos_idx[b * 100 + tt] * 50 + (k - 100)];
        else v = 0.f;
        _Float16 hi = (_Float16)v;
        xhi[idx] = hi;
        xlo[idx] = (_Float16)(v - (float)hi);
    }
}

// w1pk: [half 2][mt 32][kc 16][lane 64][4 dw] plain f16 A-frags of W1a/W1b
__global__ __launch_bounds__(256) void pack_w1(const float* __restrict__ W1,
                                               uint32_t* __restrict__ w1pk) {
    int idx = blockIdx.x * 256 + threadIdx.x;          // over 65536
    if (idx >= 65536) return;
    int l6 = idx & 63;
    int kc = (idx >> 6) & 15;
    int mt = (idx >> 10) & 31;
    int half = idx >> 15;
    int row = mt * 16 + (l6 & 15);
    int k0 = kc * 32 + (l6 >> 4) * 8;
    const float* src = &W1[(size_t)row * 1024 + half * 512 + k0];
    uint4 o;
    o.x = pack2h((_Float16)src[0], (_Float16)src[1]);
    o.y = pack2h((_Float16)src[2], (_Float16)src[3]);
    o.z = pack2h((_Float16)src[4], (_Float16)src[5]);
    o.w = pack2h((_Float16)src[6], (_Float16)src[7]);
    *(uint4*)&w1pk[(size_t)idx * 4] = o;
}

// zero only the pad row i=100 (scorer writes every (i<100, j<101) cell)
__global__ __launch_bounds__(256) void zero_pad(float* __restrict__ out) {
    int idx = blockIdx.x * 256 + threadIdx.x;
    if (idx < 16 * 101) {
        int b = idx / 101, j = idx % 101;
        out[((size_t)b * 101 + 100) * 101 + j] = 0.f;
    }
}

// ---------------- MFMA gx GEMM v2 (occupancy-tiled) ----------------
__global__ __launch_bounds__(256) void gemm_gx(const _Float16* __restrict__ xhi,
                                               const _Float16* __restrict__ xlo,
                                               const uint32_t* __restrict__ wpk_base,
                                               const float* __restrict__ bias_base,
                                               float* __restrict__ gxf_base,
                                               int KC, int ldx) {
    const int d = blockIdx.z;
    const uint32_t* wpk = wpk_base + (size_t)d * 262144;
    const float* bias = bias_base + d * 1024;
    float* gxf_d = gxf_base + (size_t)d * 1638400;

    const int t = threadIdx.x;
    const int wv = t >> 6, l = t & 63;
    const int cgrp = l >> 4;
    const int m0t = blockIdx.x * 4;
    const int n0 = blockIdx.y * 64;
    const int tk0 = n0 + wv * 16 + (l & 15);

    f32x4 acc[4];
#pragma unroll
    for (int mt = 0; mt < 4; ++mt) acc[mt] = (f32x4){0.f, 0.f, 0.f, 0.f};

    for (int kc = 0; kc < KC; ++kc) {
        const int koff = kc * 32 + cgrp * 8;
        f16x8 bh = *(const f16x8*)&xhi[(size_t)tk0 * ldx + koff];
        f16x8 bl = *(const f16x8*)&xlo[(size_t)tk0 * ldx + koff];
#pragma unroll
        for (int mt = 0; mt < 4; ++mt) {
            uint4 a = *(const uint4*)&wpk[(((size_t)(m0t + mt) * 16 + kc) * 64 + l) * 4];
            acc[mt] = MFMA16(a, bh, acc[mt]);
            acc[mt] = MFMA16(a, bl, acc[mt]);
        }
    }
    const int b = l & 15;
    const int tt = tk0 >> 4;
#pragma unroll
    for (int mt = 0; mt < 4; ++mt) {
        int mtg = m0t + mt;
        f32x4 bv;
#pragma unroll
        for (int r = 0; r < 4; ++r) bv[r] = bias[mtg * 16 + cgrp * 4 + r];
        size_t off = ((size_t)b * 100 + tt) * 1024 + mtg * 16 + cgrp * 4;
        *(f32x4*)&gxf_d[off] = acc[mt] + bv;
    }
}

// ---------------- MFMA W1 GEMM v2 (occupancy-tiled) ----------------
__global__ __launch_bounds__(256) void gemm_w1(const _Float16* __restrict__ xhi,
                                               const _Float16* __restrict__ xlo,
                                               const uint32_t* __restrict__ wpk_base,
                                               float* __restrict__ outp) {
    const int half = blockIdx.z;
    const uint32_t* wpk = wpk_base + (size_t)half * 131072;
    const int coff = half * 512;

    const int t = threadIdx.x;
    const int wv = t >> 6, l = t & 63;
    const int cgrp = l >> 4;
    const int m0t = blockIdx.x * 4;
    const int n0 = blockIdx.y * 64;
    const int tk0 = n0 + wv * 16 + (l & 15);

    f32x4 acc[4];
#pragma unroll
    for (int mt = 0; mt < 4; ++mt) acc[mt] = (f32x4){0.f, 0.f, 0.f, 0.f};

    for (int kc = 0; kc < 16; ++kc) {
        const int koff = kc * 32 + cgrp * 8;
        f16x8 bh = *(const f16x8*)&xhi[(size_t)tk0 * 512 + koff];
        f16x8 bl = *(const f16x8*)&xlo[(size_t)tk0 * 512 + koff];
#pragma unroll
        for (int mt = 0; mt < 4; ++mt) {
            uint4 a = *(const uint4*)&wpk[(((size_t)(m0t + mt) * 16 + kc) * 64 + l) * 4];
            acc[mt] = MFMA16(a, bh, acc[mt]);
            acc[mt] = MFMA16(a, bl, acc[mt]);
        }
    }
#pragma unroll
    for (int mt = 0; mt < 4; ++mt) {
        int mtg = m0t + mt;
        *(f32x4*)&outp[(size_t)tk0 * 1024 + coff + mtg * 16 + cgrp * 4] = acc[mt];
    }
}

// ---------------- LSTM v11: v9 core with h broadcast via global/L2 (VMEM pipe) ----
// 32 blocks (dir,batch); 1024 thr = 16 waves; wave w owns gate-rows [w*64,(w+1)*64).
// Weights: 23 frags VGPR + 9 frags LDS (144 KB). B = h read from per-block GLOBAL
// buffer (global_load_dwordx4, L2 broadcast) -> offloads 128 LDS instr/step to the
// VMEM pipe. Same barrier structure as v9: reads before barrier1, h writes after,
// barrier2 (vmcnt drain) publishes.
__global__ __launch_bounds__(1024, 4) void lstm_v11(const float* __restrict__ gx,
                                                    const uint32_t* __restrict__ whhpk_layer,
                                                    _Float16* __restrict__ hgl,
                                                    _Float16* __restrict__ xhi,
                                                    _Float16* __restrict__ xlo) {
    extern __shared__ uint32_t smem[];
    uint32_t* wtail = smem;                    // 16*9*64*4 = 36864 dw (144 KB)
    float*    gbuf  = (float*)(smem + 36864);  // 1024 f32

    const int d = blockIdx.x >> 4;
    const int b = blockIdx.x & 15;
    const int t = threadIdx.x;
    const int w = t >> 6;
    const int l = t & 63;
    const int cgrp = l >> 4;

    uint4 wreg[23];
    const uint32_t* wsrc = whhpk_layer + (size_t)d * 131072 + ((size_t)w * 4 * 8) * 256;
#pragma unroll
    for (int mtl = 0; mtl < 4; ++mtl)
#pragma unroll
        for (int kc = 0; kc < 8; ++kc) {
            int f = mtl * 8 + kc;
            uint4 v = *(const uint4*)&wsrc[((size_t)mtl * 8 + kc) * 256 + l * 4];
            if (f < 23) wreg[f] = v;
            else *(uint4*)&wtail[((w * 9 + (f - 23)) * 64 + l) * 4] = v;
        }
    _Float16* hg = hgl + (size_t)(d * 16 + b) * 256;     // this block's h buffer
    const uint4* hg4 = (const uint4*)hg;                 // 32 uint4 = 256 f16
    if (t < 128) ((uint32_t*)hg)[t] = 0u;
    float creg = 0.f;
    float gvi = 0.f, gvf = 0.f, gvg = 0.f, gvo = 0.f;
    const float* gxb = gx + ((size_t)(d * 16 + b)) * 102400;   // [tt][1024]
    if (t < 256) {
        int tt0 = d ? NL - 1 : 0;
        gvi = gxb[(size_t)tt0 * 1024 + t];
        gvf = gxb[(size_t)tt0 * 1024 + 256 + t];
        gvg = gxb[(size_t)tt0 * 1024 + 512 + t];
        gvo = gxb[(size_t)tt0 * 1024 + 768 + t];
    }
    __syncthreads();   // drains the h-init stores (vmcnt 0)

    for (int s = 0; s < NL; ++s) {
        const int tt = d ? (NL - 1 - s) : s;
        f32x4 acc0 = {0.f, 0.f, 0.f, 0.f};
        f32x4 acc1 = {0.f, 0.f, 0.f, 0.f};
        f32x4 acc2 = {0.f, 0.f, 0.f, 0.f};
        f32x4 acc3 = {0.f, 0.f, 0.f, 0.f};
#pragma unroll
        for (int kc = 0; kc < 8; ++kc) {
            uint4 braw = hg4[kc * 4 + cgrp];             // global L2 broadcast read
            f16x8 B = __builtin_bit_cast(f16x8, braw);
            acc0 = MFMA16(wreg[kc], B, acc0);
            acc1 = MFMA16(wreg[8 + kc], B, acc1);
            uint4 a2raw = (kc < 7) ? wreg[16 + kc]
                                   : *(const uint4*)&wtail[((w * 9 + 0) * 64 + l) * 4];
            acc2 = MFMA16(a2raw, B, acc2);
            uint4 a3raw = *(const uint4*)&wtail[((w * 9 + kc + 1) * 64 + l) * 4];
            acc3 = MFMA16(a3raw, B, acc3);
        }
        if ((l & 15) == 0) {
            *(f32x4*)&gbuf[w * 64 +  0 + cgrp * 4] = acc0;
            *(f32x4*)&gbuf[w * 64 + 16 + cgrp * 4] = acc1;
            *(f32x4*)&gbuf[w * 64 + 32 + cgrp * 4] = acc2;
            *(f32x4*)&gbuf[w * 64 + 48 + cgrp * 4] = acc3;
        }
        __syncthreads();   // all B reads of h(s-1) complete; gbuf published
        if (t < 256) {
            float gi = gbuf[t] + gvi;
            float gf = gbuf[256 + t] + gvf;
            float gg = gbuf[512 + t] + gvg;
            float go = gbuf[768 + t] + gvo;
            float cn = fmaf(sigm(gf), creg, sigm(gi) * tanh_(gg));
            creg = cn;
            float hn = sigm(go) * tanh_(cn);
            _Float16 hh = (_Float16)hn;
            hg[t] = hh;                                   // global h write
            const size_t xb = ((size_t)tt * 16 + b) * 512 + d * 256 + t;
            xhi[xb] = hh;
            xlo[xb] = (_Float16)(hn - (float)hh);
            if (s + 1 < NL) {
                int tn = d ? (NL - 2 - s) : (s + 1);
                gvi = gxb[(size_t)tn * 1024 + t];
                gvf = gxb[(size_t)tn * 1024 + 256 + t];
                gvg = gxb[(size_t)tn * 1024 + 512 + t];
                gvo = gxb[(size_t)tn * 1024 + 768 + t];
            }
        }
        __syncthreads();   // vmcnt(0) drain publishes h(s) before next step's reads
    }
}

// ---------------- MFMA scorer (token' = i*16+b indexing) ----------------
__global__ __launch_bounds__(256) void scorer_v2(const float* __restrict__ hfr,
                                                 const uint32_t* __restrict__ w2pk,
                                                 const float* __restrict__ b1,
                                                 const float* __restrict__ b2,
                                                 const float* __restrict__ W3,
                                                 const float* __restrict__ b3,
                                                 const int* __restrict__ sen_lens,
                                                 float* __restrict__ out) {
    __shared__ float hfs[16][520];
    __shared__ float hrs[8][520];

    const int t = threadIdx.x;
    const int wv = t >> 6, l = t & 63;
    const int cgrp = l >> 4;
    const int b = blockIdx.z;
    const int i0 = blockIdx.x * 16;
    const int j0 = blockIdx.y * 8;

#pragma unroll
    for (int rep = 0; rep < 8; ++rep) {
        int slot = rep * 256 + t;
        int row = slot >> 7, c4 = slot & 127;
        int i = i0 + row;
        float4 v = make_float4(0.f, 0.f, 0.f, 0.f);
        if (i < 100) v = *(const float4*)&hfr[((size_t)(i * 16 + b)) * 1024 + c4 * 4];
        *(float4*)&hfs[row][c4 * 4] = v;
    }
#pragma unroll
    for (int rep = 0; rep < 4; ++rep) {
        int slot = rep * 256 + t;
        int row = slot >> 7, c4 = slot & 127;
        int j = j0 + row;
        float4 bv = *(const float4*)&b1[c4 * 4];
        float4 v = make_float4(0.f, 0.f, 0.f, 0.f);
        if (j >= 1 && j <= 100)
            v = *(const float4*)&hfr[((size_t)((j - 1) * 16 + b)) * 1024 + 512 + c4 * 4];
        v.x += bv.x; v.y += bv.y; v.z += bv.z; v.w += bv.w;
        *(float4*)&hrs[row][c4 * 4] = v;
    }

    float b2r[8], w3r[8];
#pragma unroll
    for (int nt = 0; nt < 8; ++nt) {
        b2r[nt] = b2[nt * 16 + (l & 15)];
        w3r[nt] = W3[nt * 16 + (l & 15)];
    }
    f32x4 accA[8], accB[8];
#pragma unroll
    for (int nt = 0; nt < 8; ++nt) {
        accA[nt] = (f32x4){0.f, 0.f, 0.f, 0.f};
        accB[nt] = (f32x4){0.f, 0.f, 0.f, 0.f};
    }
    const int p0 = (wv * 2) * 16 + (l & 15);
    const int p1 = (wv * 2 + 1) * 16 + (l & 15);
    const int ilA = p0 >> 3, jlA = p0 & 7;
    const int ilB = p1 >> 3, jlB = p1 & 7;
    __syncthreads();

    for (int kc = 0; kc < 16; ++kc) {
        const int k0 = kc * 32 + cgrp * 8;
        f16x8 ahi0, alo0, ahi1, alo1;
        {
            f32x4 f0 = *(const f32x4*)&hfs[ilA][k0];
            f32x4 f1 = *(const f32x4*)&hfs[ilA][k0 + 4];
            f32x4 r0 = *(const f32x4*)&hrs[jlA][k0];
            f32x4 r1 = *(const f32x4*)&hrs[jlA][k0 + 4];
#pragma unroll
            for (int j = 0; j < 4; ++j) {
                float v = fmaxf(f0[j] + r0[j], 0.f);
                _Float16 hi = (_Float16)v;
                ahi0[j] = hi; alo0[j] = (_Float16)(v - (float)hi);
                v = fmaxf(f1[j] + r1[j], 0.f);
                hi = (_Float16)v;
                ahi0[4 + j] = hi; alo0[4 + j] = (_Float16)(v - (float)hi);
            }
        }
        {
            f32x4 f0 = *(const f32x4*)&hfs[ilB][k0];
            f32x4 f1 = *(const f32x4*)&hfs[ilB][k0 + 4];
            f32x4 r0 = *(const f32x4*)&hrs[jlB][k0];
            f32x4 r1 = *(const f32x4*)&hrs[jlB][k0 + 4];
#pragma unroll
            for (int j = 0; j < 4; ++j) {
                float v = fmaxf(f0[j] + r0[j], 0.f);
                _Float16 hi = (_Float16)v;
                ahi1[j] = hi; alo1[j] = (_Float16)(v - (float)hi);
                v = fmaxf(f1[j] + r1[j], 0.f);
                hi = (_Float16)v;
                ahi1[4 + j] = hi; alo1[4 + j] = (_Float16)(v - (float)hi);
            }
        }
#pragma unroll
        for (int nt = 0; nt < 8; ++nt) {
            f16x8 bhi = __builtin_bit_cast(f16x8,
                *(const uint4*)&w2pk[((((size_t)kc * 2 + 0) * 8 + nt) * 64 + l) * 4]);
            f16x8 blo = __builtin_bit_cast(f16x8,
                *(const uint4*)&w2pk[((((size_t)kc * 2 + 1) * 8 + nt) * 64 + l) * 4]);
            accA[nt] = __builtin_amdgcn_mfma_f32_16x16x32_f16(ahi0, bhi, accA[nt], 0, 0, 0);
            accA[nt] = __builtin_amdgcn_mfma_f32_16x16x32_f16(ahi0, blo, accA[nt], 0, 0, 0);
            accA[nt] = __builtin_amdgcn_mfma_f32_16x16x32_f16(alo0, bhi, accA[nt], 0, 0, 0);
            accB[nt] = __builtin_amdgcn_mfma_f32_16x16x32_f16(ahi1, bhi, accB[nt], 0, 0, 0);
            accB[nt] = __builtin_amdgcn_mfma_f32_16x16x32_f16(ahi1, blo, accB[nt], 0, 0, 0);
            accB[nt] = __builtin_amdgcn_mfma_f32_16x16x32_f16(alo1, bhi, accB[nt], 0, 0, 0);
        }
    }
    float sp0[4] = {0.f, 0.f, 0.f, 0.f};
    float sp1[4] = {0.f, 0.f, 0.f, 0.f};
#pragma unroll
    for (int nt = 0; nt < 8; ++nt)
#pragma unroll
        for (int r = 0; r < 4; ++r) {
            sp0[r] += fmaxf(accA[nt][r] + b2r[nt], 0.f) * w3r[nt];
            sp1[r] += fmaxf(accB[nt][r] + b2r[nt], 0.f) * w3r[nt];
        }
#pragma unroll
    for (int r = 0; r < 4; ++r) {
#pragma unroll
        for (int off = 1; off < 16; off <<= 1) {
            sp0[r] += __shfl_xor(sp0[r], off);
            sp1[r] += __shfl_xor(sp1[r], off);
        }
    }
    if ((l & 15) == 0) {
        float bias3 = b3[0];
        int sl = sen_lens[b];
#pragma unroll
        for (int mtl = 0; mtl < 2; ++mtl)
#pragma unroll
            for (int r = 0; r < 4; ++r) {
                int p = (wv * 2 + mtl) * 16 + cgrp * 4 + r;
                int i = i0 + (p >> 3), j = j0 + (p & 7);
                if (i < 100 && j < 101) {
                    float v = (mtl == 0 ? sp0[r] : sp1[r]) + bias3;
                    if (!((i < sl) && (j <= sl)) || (i == 0 && j == 0)) v = 0.f;
                    out[((size_t)b * 101 + i) * 101 + j] = v;
                }
            }
    }
}

// ---------------- launcher ----------------
extern "C" void kernel_launch(void* const* d_in, const int* in_sizes, int n_in,
                              void* d_out, int out_size, void* d_ws, size_t ws_size,
                              hipStream_t stream) {
    const float* we       = (const float*)d_in[0];
    const int*   pos_idx  = (const int*)d_in[1];
    const int*   sen_lens = (const int*)d_in[2];
    const float* pos_emb  = (const float*)d_in[3];
    const float* w_ih0    = (const float*)d_in[4];
    const float* w_hh0    = (const float*)d_in[5];
    const float* b_ih0    = (const float*)d_in[6];
    const float* b_hh0    = (const float*)d_in[7];
    const float* w_ih     = (const float*)d_in[8];
    const float* w_hh     = (const float*)d_in[9];
    const float* b_ih     = (const float*)d_in[10];
    const float* b_hh     = (const float*)d_in[11];
    const float* W1       = (const float*)d_in[12];
    const float* b1       = (const float*)d_in[13];
    const float* W2       = (const float*)d_in[14];
    const float* b2       = (const float*)d_in[15];
    const float* W3       = (const float*)d_in[16];
    const float* b3       = (const float*)d_in[17];
    float* out = (float*)d_out;

    // workspace map (dw offsets)
    uint32_t* ws = (uint32_t*)d_ws;
    _Float16* x0hi  = (_Float16*)(ws + 0);          // 128000 dw
    _Float16* x0lo  = (_Float16*)(ws + 128000);     // 128000
    float*    gxf   = (float*)(ws + 256000);        // 3276800  [d][b][tt][1024]
    _Float16* xAhi  = (_Float16*)(ws + 3532800);    // 409600
    _Float16* xAlo  = (_Float16*)(ws + 3942400);    // 409600
    _Float16* xBhi  = (_Float16*)(ws + 5171200);    // 409600
    _Float16* xBlo  = (_Float16*)(ws + 5580800);    // 409600
    float*    hfr   = (float*)(ws + 6809600);       // 1638400
    uint32_t* wihpk = ws + 8448000;                 // 2097152 (8 dl x 262144)
    uint32_t* whhpk = ws + 10545152;                // 1048576 (4 layers x 262144)
    uint32_t* w2pk  = ws + 11593728;                // 65536
    float*    biasp = (float*)(ws + 11659264);      // 8192
    _Float16* hgl   = (_Float16*)(ws + 11667456);   // 4096 dw = 8192 f16

    pack_all<<<4168, 256, 0, stream>>>(w_hh0, w_hh, w_ih0, w_ih, W2,
                                       b_ih0, b_hh0, b_ih, b_hh,
                                       we, pos_idx, pos_emb,
                                       whhpk, wihpk, w2pk, biasp, x0hi, x0lo);

    const int LSTM_SMEM = 37888 * 4;   // 151552 B (144K wtail + 4K gbuf)

    // layer 0 (K = 160 -> KC = 5); both dirs in one launch (grid.z)
    gemm_gx<<<dim3(16, 25, 2), 256, 0, stream>>>(
        x0hi, x0lo, wihpk, biasp, gxf, 5, 160);
    lstm_v11<<<32, 1024, LSTM_SMEM, stream>>>(gxf, whhpk, hgl, xAhi, xAlo);

    _Float16* xih = xAhi; _Float16* xil = xAlo;
    _Float16* xoh = xBhi; _Float16* xol = xBlo;
    for (int lyr = 1; lyr < 4; ++lyr) {
        int dlbase = 2 + (lyr - 1) * 2;
        gemm_gx<<<dim3(16, 25, 2), 256, 0, stream>>>(
            xih, xil, wihpk + (size_t)dlbase * 262144,
            biasp + lyr * 2048, gxf, 16, 512);
        lstm_v11<<<32, 1024, LSTM_SMEM, stream>>>(gxf, whhpk + (size_t)lyr * 262144,
                                                  hgl, xoh, xol);
        _Float16* th = xih; xih = xoh; xoh = th;
        _Float16* tl = xil; xil = xol; xol = tl;
    }
    // final layer hi/lo in xih/xil (token'-major [t*16+b][512])

    // W1 projections via MFMA; w1pk reuses the (now dead) gxf region
    uint32_t* w1pk = (uint32_t*)gxf;   // 262144 dw needed, 3276800 available
    pack_w1<<<256, 256, 0, stream>>>(W1, w1pk);
    gemm_w1<<<dim3(8, 25, 2), 256, 0, stream>>>(xih, xil, w1pk, hfr);

    zero_pad<<<7, 256, 0, stream>>>(out);
    scorer_v2<<<dim3(7, 13, 16), 256, 0, stream>>>(hfr, w2pk, b1, b2, W3, b3,
                                                   sen_lens, out);
}

// Round 14
// 990.363 us; speedup vs baseline: 1.2683x; 1.2683x over previous
//
#include <hip/hip_runtime.h>
#include <stdint.h>

#define NB 16
#define NL 100
#define NOUT (16*101*101)

typedef _Float16 f16x8 __attribute__((ext_vector_type(8)));
typedef float f32x4 __attribute__((ext_vector_type(4)));

__device__ __forceinline__ float sigm(float x) {
    x = fminf(fmaxf(x, -30.f), 30.f);
    return 1.f / (1.f + __expf(-x));
}
__device__ __forceinline__ float tanh_(float x) {
    x = fminf(fmaxf(x, -15.f), 15.f);
    float t = __expf(2.f * x);
    return (t - 1.f) / (t + 1.f);
}
__device__ __forceinline__ uint32_t pack2h(_Float16 a, _Float16 b) {
    return (uint32_t)__builtin_bit_cast(uint16_t, a) |
           ((uint32_t)__builtin_bit_cast(uint16_t, b) << 16);
}
#define MFMA16(A, B, C) __builtin_amdgcn_mfma_f32_16x16x32_f16( \
    __builtin_bit_cast(f16x8, A), (B), (C), 0, 0, 0)

// ---------------- fused pack kernel ----------------
// segments: [0,262144) whh | [262144,786432) wih | [786432,802816) w2
//           [802816,811008) bias | [811008,1067008) x0
__global__ __launch_bounds__(256) void pack_all(const float* __restrict__ w_hh0,
                                                const float* __restrict__ w_hh,
                                                const float* __restrict__ w_ih0,
                                                const float* __restrict__ w_ih,
                                                const float* __restrict__ W2,
                                                const float* __restrict__ b_ih0,
                                                const float* __restrict__ b_hh0,
                                                const float* __restrict__ b_ih,
                                                const float* __restrict__ b_hh,
                                                const float* __restrict__ we,
                                                const int* __restrict__ pos_idx,
                                                const float* __restrict__ pos_emb,
                                                uint32_t* __restrict__ whhpk,
                                                uint32_t* __restrict__ wihpk,
                                                uint32_t* __restrict__ w2pk,
                                                float* __restrict__ biasp,
                                                _Float16* __restrict__ xhi,
                                                _Float16* __restrict__ xlo) {
    int gid = blockIdx.x * 256 + threadIdx.x;
    if (gid < 262144) {
        int idx = gid;
        int l6 = idx & 63;
        int kc = (idx >> 6) & 7;
        int mt = (idx >> 9) & 63;
        int ld = idx >> 15;
        int layer = ld >> 1, d = ld & 1;
        int row = mt * 16 + (l6 & 15);
        int k0 = kc * 32 + (l6 >> 4) * 8;
        const float* src = (layer == 0)
            ? &w_hh0[((size_t)d * 1024 + row) * 256]
            : &w_hh[(((size_t)(layer - 1) * 2 + d) * 1024 + row) * 256];
        uint4 o;
        o.x = pack2h((_Float16)src[k0 + 0], (_Float16)src[k0 + 1]);
        o.y = pack2h((_Float16)src[k0 + 2], (_Float16)src[k0 + 3]);
        o.z = pack2h((_Float16)src[k0 + 4], (_Float16)src[k0 + 5]);
        o.w = pack2h((_Float16)src[k0 + 6], (_Float16)src[k0 + 7]);
        *(uint4*)&whhpk[(size_t)idx * 4] = o;
    } else if (gid < 786432) {
        int idx = gid - 262144;
        int l6 = idx & 63;
        int kc = (idx >> 6) & 15;
        int mt = (idx >> 10) & 63;
        int dl = idx >> 16;
        int row = mt * 16 + (l6 & 15);
        int k0 = kc * 32 + (l6 >> 4) * 8;
        float v[8];
#pragma unroll
        for (int j = 0; j < 8; ++j) {
            int k = k0 + j;
            if (dl < 2) v[j] = (k < 150) ? w_ih0[((size_t)dl * 1024 + row) * 150 + k] : 0.f;
            else        v[j] = w_ih[((size_t)(dl - 2) * 1024 + row) * 512 + k];
        }
        uint4 o;
        o.x = pack2h((_Float16)v[0], (_Float16)v[1]);
        o.y = pack2h((_Float16)v[2], (_Float16)v[3]);
        o.z = pack2h((_Float16)v[4], (_Float16)v[5]);
        o.w = pack2h((_Float16)v[6], (_Float16)v[7]);
        *(uint4*)&wihpk[(size_t)idx * 4] = o;
    } else if (gid < 802816) {
        int idx = gid - 786432;
        int l6 = idx & 63;
        int nt = (idx >> 6) & 7;
        int sp = (idx >> 9) & 1;
        int kc = idx >> 10;
        int ch = nt * 16 + (l6 & 15);
        int k0 = kc * 32 + (l6 >> 4) * 8;
        uint32_t dw[4];
#pragma unroll
        for (int dwi = 0; dwi < 4; ++dwi) {
            float x0 = W2[(size_t)ch * 512 + k0 + dwi * 2 + 0];
            float x1 = W2[(size_t)ch * 512 + k0 + dwi * 2 + 1];
            _Float16 h0 = (_Float16)x0, h1 = (_Float16)x1;
            _Float16 v0 = sp ? (_Float16)(x0 - (float)h0) : h0;
            _Float16 v1 = sp ? (_Float16)(x1 - (float)h1) : h1;
            dw[dwi] = pack2h(v0, v1);
        }
        *(uint4*)&w2pk[(size_t)idx * 4] = make_uint4(dw[0], dw[1], dw[2], dw[3]);
    } else if (gid < 811008) {
        int idx = gid - 802816;
        int g = idx & 1023;
        int ld = idx >> 10;
        int l = ld >> 1, d = ld & 1;
        float v;
        if (l == 0) v = b_ih0[d * 1024 + g] + b_hh0[d * 1024 + g];
        else {
            size_t o = ((size_t)(l - 1) * 2 + d) * 1024 + g;
            v = b_ih[o] + b_hh[o];
        }
        biasp[idx] = v;
    } else if (gid < 1067008) {
        int idx = gid - 811008;
        int mp = idx / 160, k = idx % 160;
        int tt = mp >> 4, b = mp & 15;
        float v;
        if (k < 100) v = we[((size_t)b * 100 + tt) * 100 + k];
        else if (k < 150) v = pos_emb[(size_t)pos_idx[b * 100 + tt] * 50 + (k - 100)];
        else v = 0.f;
        _Float16 hi = (_Float16)v;
        xhi[idx] = hi;
        xlo[idx] = (_Float16)(v - (float)hi);
    }
}

// w1pk: [half 2][mt 32][kc 16][lane 64][4 dw] plain f16 A-frags of W1a/W1b
__global__ __launch_bounds__(256) void pack_w1(const float* __restrict__ W1,
                                               uint32_t* __restrict__ w1pk) {
    int idx = blockIdx.x * 256 + threadIdx.x;          // over 65536
    if (idx >= 65536) return;
    int l6 = idx & 63;
    int kc = (idx >> 6) & 15;
    int mt = (idx >> 10) & 31;
    int half = idx >> 15;
    int row = mt * 16 + (l6 & 15);
    int k0 = kc * 32 + (l6 >> 4) * 8;
    const float* src = &W1[(size_t)row * 1024 + half * 512 + k0];
    uint4 o;
    o.x = pack2h((_Float16)src[0], (_Float16)src[1]);
    o.y = pack2h((_Float16)src[2], (_Float16)src[3]);
    o.z = pack2h((_Float16)src[4], (_Float16)src[5]);
    o.w = pack2h((_Float16)src[6], (_Float16)src[7]);
    *(uint4*)&w1pk[(size_t)idx * 4] = o;
}

// zero only the pad row i=100 (scorer writes every (i<100, j<101) cell)
__global__ __launch_bounds__(256) void zero_pad(float* __restrict__ out) {
    int idx = blockIdx.x * 256 + threadIdx.x;
    if (idx < 16 * 101) {
        int b = idx / 101, j = idx % 101;
        out[((size_t)b * 101 + 100) * 101 + j] = 0.f;
    }
}

// ---------------- MFMA gx GEMM v2 (occupancy-tiled) ----------------
__global__ __launch_bounds__(256) void gemm_gx(const _Float16* __restrict__ xhi,
                                               const _Float16* __restrict__ xlo,
                                               const uint32_t* __restrict__ wpk_base,
                                               const float* __restrict__ bias_base,
                                               float* __restrict__ gxf_base,
                                               int KC, int ldx) {
    const int d = blockIdx.z;
    const uint32_t* wpk = wpk_base + (size_t)d * 262144;
    const float* bias = bias_base + d * 1024;
    float* gxf_d = gxf_base + (size_t)d * 1638400;

    const int t = threadIdx.x;
    const int wv = t >> 6, l = t & 63;
    const int cgrp = l >> 4;
    const int m0t = blockIdx.x * 4;
    const int n0 = blockIdx.y * 64;
    const int tk0 = n0 + wv * 16 + (l & 15);

    f32x4 acc[4];
#pragma unroll
    for (int mt = 0; mt < 4; ++mt) acc[mt] = (f32x4){0.f, 0.f, 0.f, 0.f};

    for (int kc = 0; kc < KC; ++kc) {
        const int koff = kc * 32 + cgrp * 8;
        f16x8 bh = *(const f16x8*)&xhi[(size_t)tk0 * ldx + koff];
        f16x8 bl = *(const f16x8*)&xlo[(size_t)tk0 * ldx + koff];
#pragma unroll
        for (int mt = 0; mt < 4; ++mt) {
            uint4 a = *(const uint4*)&wpk[(((size_t)(m0t + mt) * 16 + kc) * 64 + l) * 4];
            acc[mt] = MFMA16(a, bh, acc[mt]);
            acc[mt] = MFMA16(a, bl, acc[mt]);
        }
    }
    const int b = l & 15;
    const int tt = tk0 >> 4;
#pragma unroll
    for (int mt = 0; mt < 4; ++mt) {
        int mtg = m0t + mt;
        f32x4 bv;
#pragma unroll
        for (int r = 0; r < 4; ++r) bv[r] = bias[mtg * 16 + cgrp * 4 + r];
        size_t off = ((size_t)b * 100 + tt) * 1024 + mtg * 16 + cgrp * 4;
        *(f32x4*)&gxf_d[off] = acc[mt] + bv;
    }
}

// ---------------- MFMA W1 GEMM v2 (occupancy-tiled) ----------------
__global__ __launch_bounds__(256) void gemm_w1(const _Float16* __restrict__ xhi,
                                               const _Float16* __restrict__ xlo,
                                               const uint32_t* __restrict__ wpk_base,
                                               float* __restrict__ outp) {
    const int half = blockIdx.z;
    const uint32_t* wpk = wpk_base + (size_t)half * 131072;
    const int coff = half * 512;

    const int t = threadIdx.x;
    const int wv = t >> 6, l = t & 63;
    const int cgrp = l >> 4;
    const int m0t = blockIdx.x * 4;
    const int n0 = blockIdx.y * 64;
    const int tk0 = n0 + wv * 16 + (l & 15);

    f32x4 acc[4];
#pragma unroll
    for (int mt = 0; mt < 4; ++mt) acc[mt] = (f32x4){0.f, 0.f, 0.f, 0.f};

    for (int kc = 0; kc < 16; ++kc) {
        const int koff = kc * 32 + cgrp * 8;
        f16x8 bh = *(const f16x8*)&xhi[(size_t)tk0 * 512 + koff];
        f16x8 bl = *(const f16x8*)&xlo[(size_t)tk0 * 512 + koff];
#pragma unroll
        for (int mt = 0; mt < 4; ++mt) {
            uint4 a = *(const uint4*)&wpk[(((size_t)(m0t + mt) * 16 + kc) * 64 + l) * 4];
            acc[mt] = MFMA16(a, bh, acc[mt]);
            acc[mt] = MFMA16(a, bl, acc[mt]);
        }
    }
#pragma unroll
    for (int mt = 0; mt < 4; ++mt) {
        int mtg = m0t + mt;
        *(f32x4*)&outp[(size_t)tk0 * 1024 + coff + mtg * 16 + cgrp * 4] = acc[mt];
    }
}

// ---------------- LSTM v9 core (proven 204 us/layer, LDS h broadcast) ----------------
// 32 blocks (dir,batch); 1024 thr = 16 waves; wave w owns gate-rows [w*64,(w+1)*64).
// Weights: 23 frags VGPR + 9 frags LDS (144 KB). B = h broadcast from LDS.
// gbuf gate exchange; activation on t<256 with gx prefetched in regs.
__global__ __launch_bounds__(1024, 4) void lstm_v9(const float* __restrict__ gx,
                                                   const uint32_t* __restrict__ whhpk_layer,
                                                   _Float16* __restrict__ xhi,
                                                   _Float16* __restrict__ xlo) {
    extern __shared__ uint32_t smem[];
    uint32_t* wtail = smem;                    // 16*9*64*4 = 36864 dw (144 KB)
    float*    gbuf  = (float*)(smem + 36864);  // 1024 f32
    uint32_t* hsta  = smem + 37888;            // 128 dw = 256 f16

    const int d = blockIdx.x >> 4;
    const int b = blockIdx.x & 15;
    const int t = threadIdx.x;
    const int w = t >> 6;
    const int l = t & 63;
    const int cgrp = l >> 4;

    uint4 wreg[23];
    const uint32_t* wsrc = whhpk_layer + (size_t)d * 131072 + ((size_t)w * 4 * 8) * 256;
#pragma unroll
    for (int mtl = 0; mtl < 4; ++mtl)
#pragma unroll
        for (int kc = 0; kc < 8; ++kc) {
            int f = mtl * 8 + kc;
            uint4 v = *(const uint4*)&wsrc[((size_t)mtl * 8 + kc) * 256 + l * 4];
            if (f < 23) wreg[f] = v;
            else *(uint4*)&wtail[((w * 9 + (f - 23)) * 64 + l) * 4] = v;
        }
    if (t < 128) hsta[t] = 0u;
    float creg = 0.f;
    float gvi = 0.f, gvf = 0.f, gvg = 0.f, gvo = 0.f;
    const float* gxb = gx + ((size_t)(d * 16 + b)) * 102400;   // [tt][1024]
    if (t < 256) {
        int tt0 = d ? NL - 1 : 0;
        gvi = gxb[(size_t)tt0 * 1024 + t];
        gvf = gxb[(size_t)tt0 * 1024 + 256 + t];
        gvg = gxb[(size_t)tt0 * 1024 + 512 + t];
        gvo = gxb[(size_t)tt0 * 1024 + 768 + t];
    }
    __syncthreads();

    for (int s = 0; s < NL; ++s) {
        const int tt = d ? (NL - 1 - s) : s;
        f32x4 acc0 = {0.f, 0.f, 0.f, 0.f};
        f32x4 acc1 = {0.f, 0.f, 0.f, 0.f};
        f32x4 acc2 = {0.f, 0.f, 0.f, 0.f};
        f32x4 acc3 = {0.f, 0.f, 0.f, 0.f};
#pragma unroll
        for (int kc = 0; kc < 8; ++kc) {
            uint4 braw = *(const uint4*)&hsta[kc * 16 + cgrp * 4];
            f16x8 B = __builtin_bit_cast(f16x8, braw);
            acc0 = MFMA16(wreg[kc], B, acc0);
            acc1 = MFMA16(wreg[8 + kc], B, acc1);
            uint4 a2raw = (kc < 7) ? wreg[16 + kc]
                                   : *(const uint4*)&wtail[((w * 9 + 0) * 64 + l) * 4];
            acc2 = MFMA16(a2raw, B, acc2);
            uint4 a3raw = *(const uint4*)&wtail[((w * 9 + kc + 1) * 64 + l) * 4];
            acc3 = MFMA16(a3raw, B, acc3);
        }
        if ((l & 15) == 0) {
            *(f32x4*)&gbuf[w * 64 +  0 + cgrp * 4] = acc0;
            *(f32x4*)&gbuf[w * 64 + 16 + cgrp * 4] = acc1;
            *(f32x4*)&gbuf[w * 64 + 32 + cgrp * 4] = acc2;
            *(f32x4*)&gbuf[w * 64 + 48 + cgrp * 4] = acc3;
        }
        __syncthreads();
        if (t < 256) {
            float gi = gbuf[t] + gvi;
            float gf = gbuf[256 + t] + gvf;
            float gg = gbuf[512 + t] + gvg;
            float go = gbuf[768 + t] + gvo;
            float cn = fmaf(sigm(gf), creg, sigm(gi) * tanh_(gg));
            creg = cn;
            float hn = sigm(go) * tanh_(cn);
            _Float16 hh = (_Float16)hn;
            ((_Float16*)hsta)[t] = hh;
            const size_t xb = ((size_t)tt * 16 + b) * 512 + d * 256 + t;
            xhi[xb] = hh;
            xlo[xb] = (_Float16)(hn - (float)hh);
            if (s + 1 < NL) {
                int tn = d ? (NL - 2 - s) : (s + 1);
                gvi = gxb[(size_t)tn * 1024 + t];
                gvf = gxb[(size_t)tn * 1024 + 256 + t];
                gvg = gxb[(size_t)tn * 1024 + 512 + t];
                gvo = gxb[(size_t)tn * 1024 + 768 + t];
            }
        }
        __syncthreads();
    }
}

// ---------------- MFMA scorer (token' = i*16+b indexing) ----------------
__global__ __launch_bounds__(256) void scorer_v2(const float* __restrict__ hfr,
                                                 const uint32_t* __restrict__ w2pk,
                                                 const float* __restrict__ b1,
                                                 const float* __restrict__ b2,
                                                 const float* __restrict__ W3,
                                                 const float* __restrict__ b3,
                                                 const int* __restrict__ sen_lens,
                                                 float* __restrict__ out) {
    __shared__ float hfs[16][520];
    __shared__ float hrs[8][520];

    const int t = threadIdx.x;
    const int wv = t >> 6, l = t & 63;
    const int cgrp = l >> 4;
    const int b = blockIdx.z;
    const int i0 = blockIdx.x * 16;
    const int j0 = blockIdx.y * 8;

#pragma unroll
    for (int rep = 0; rep < 8; ++rep) {
        int slot = rep * 256 + t;
        int row = slot >> 7, c4 = slot & 127;
        int i = i0 + row;
        float4 v = make_float4(0.f, 0.f, 0.f, 0.f);
        if (i < 100) v = *(const float4*)&hfr[((size_t)(i * 16 + b)) * 1024 + c4 * 4];
        *(float4*)&hfs[row][c4 * 4] = v;
    }
#pragma unroll
    for (int rep = 0; rep < 4; ++rep) {
        int slot = rep * 256 + t;
        int row = slot >> 7, c4 = slot & 127;
        int j = j0 + row;
        float4 bv = *(const float4*)&b1[c4 * 4];
        float4 v = make_float4(0.f, 0.f, 0.f, 0.f);
        if (j >= 1 && j <= 100)
            v = *(const float4*)&hfr[((size_t)((j - 1) * 16 + b)) * 1024 + 512 + c4 * 4];
        v.x += bv.x; v.y += bv.y; v.z += bv.z; v.w += bv.w;
        *(float4*)&hrs[row][c4 * 4] = v;
    }

    float b2r[8], w3r[8];
#pragma unroll
    for (int nt = 0; nt < 8; ++nt) {
        b2r[nt] = b2[nt * 16 + (l & 15)];
        w3r[nt] = W3[nt * 16 + (l & 15)];
    }
    f32x4 accA[8], accB[8];
#pragma unroll
    for (int nt = 0; nt < 8; ++nt) {
        accA[nt] = (f32x4){0.f, 0.f, 0.f, 0.f};
        accB[nt] = (f32x4){0.f, 0.f, 0.f, 0.f};
    }
    const int p0 = (wv * 2) * 16 + (l & 15);
    const int p1 = (wv * 2 + 1) * 16 + (l & 15);
    const int ilA = p0 >> 3, jlA = p0 & 7;
    const int ilB = p1 >> 3, jlB = p1 & 7;
    __syncthreads();

    for (int kc = 0; kc < 16; ++kc) {
        const int k0 = kc * 32 + cgrp * 8;
        f16x8 ahi0, alo0, ahi1, alo1;
        {
            f32x4 f0 = *(const f32x4*)&hfs[ilA][k0];
            f32x4 f1 = *(const f32x4*)&hfs[ilA][k0 + 4];
            f32x4 r0 = *(const f32x4*)&hrs[jlA][k0];
            f32x4 r1 = *(const f32x4*)&hrs[jlA][k0 + 4];
#pragma unroll
            for (int j = 0; j < 4; ++j) {
                float v = fmaxf(f0[j] + r0[j], 0.f);
                _Float16 hi = (_Float16)v;
                ahi0[j] = hi; alo0[j] = (_Float16)(v - (float)hi);
                v = fmaxf(f1[j] + r1[j], 0.f);
                hi = (_Float16)v;
                ahi0[4 + j] = hi; alo0[4 + j] = (_Float16)(v - (float)hi);
            }
        }
        {
            f32x4 f0 = *(const f32x4*)&hfs[ilB][k0];
            f32x4 f1 = *(const f32x4*)&hfs[ilB][k0 + 4];
            f32x4 r0 = *(const f32x4*)&hrs[jlB][k0];
            f32x4 r1 = *(const f32x4*)&hrs[jlB][k0 + 4];
#pragma unroll
            for (int j = 0; j < 4; ++j) {
                float v = fmaxf(f0[j] + r0[j], 0.f);
                _Float16 hi = (_Float16)v;
                ahi1[j] = hi; alo1[j] = (_Float16)(v - (float)hi);
                v = fmaxf(f1[j] + r1[j], 0.f);
                hi = (_Float16)v;
                ahi1[4 + j] = hi; alo1[4 + j] = (_Float16)(v - (float)hi);
            }
        }
#pragma unroll
        for (int nt = 0; nt < 8; ++nt) {
            f16x8 bhi = __builtin_bit_cast(f16x8,
                *(const uint4*)&w2pk[((((size_t)kc * 2 + 0) * 8 + nt) * 64 + l) * 4]);
            f16x8 blo = __builtin_bit_cast(f16x8,
                *(const uint4*)&w2pk[((((size_t)kc * 2 + 1) * 8 + nt) * 64 + l) * 4]);
            accA[nt] = __builtin_amdgcn_mfma_f32_16x16x32_f16(ahi0, bhi, accA[nt], 0, 0, 0);
            accA[nt] = __builtin_amdgcn_mfma_f32_16x16x32_f16(ahi0, blo, accA[nt], 0, 0, 0);
            accA[nt] = __builtin_amdgcn_mfma_f32_16x16x32_f16(alo0, bhi, accA[nt], 0, 0, 0);
            accB[nt] = __builtin_amdgcn_mfma_f32_16x16x32_f16(ahi1, bhi, accB[nt], 0, 0, 0);
            accB[nt] = __builtin_amdgcn_mfma_f32_16x16x32_f16(ahi1, blo, accB[nt], 0, 0, 0);
            accB[nt] = __builtin_amdgcn_mfma_f32_16x16x32_f16(alo1, bhi, accB[nt], 0, 0, 0);
        }
    }
    float sp0[4] = {0.f, 0.f, 0.f, 0.f};
    float sp1[4] = {0.f, 0.f, 0.f, 0.f};
#pragma unroll
    for (int nt = 0; nt < 8; ++nt)
#pragma unroll
        for (int r = 0; r < 4; ++r) {
            sp0[r] += fmaxf(accA[nt][r] + b2r[nt], 0.f) * w3r[nt];
            sp1[r] += fmaxf(accB[nt][r] + b2r[nt], 0.f) * w3r[nt];
        }
#pragma unroll
    for (int r = 0; r < 4; ++r) {
#pragma unroll
        for (int off = 1; off < 16; off <<= 1) {
            sp0[r] += __shfl_xor(sp0[r], off);
            sp1[r] += __shfl_xor(sp1[r], off);
        }
    }
    if ((l & 15) == 0) {
        float bias3 = b3[0];
        int sl = sen_lens[b];
#pragma unroll
        for (int mtl = 0; mtl < 2; ++mtl)
#pragma unroll
            for (int r = 0; r < 4; ++r) {
                int p = (wv * 2 + mtl) * 16 + cgrp * 4 + r;
                int i = i0 + (p >> 3), j = j0 + (p & 7);
                if (i < 100 && j < 101) {
                    float v = (mtl == 0 ? sp0[r] : sp1[r]) + bias3;
                    if (!((i < sl) && (j <= sl)) || (i == 0 && j == 0)) v = 0.f;
                    out[((size_t)b * 101 + i) * 101 + j] = v;
                }
            }
    }
}

// ---------------- launcher ----------------
extern "C" void kernel_launch(void* const* d_in, const int* in_sizes, int n_in,
                              void* d_out, int out_size, void* d_ws, size_t ws_size,
                              hipStream_t stream) {
    const float* we       = (const float*)d_in[0];
    const int*   pos_idx  = (const int*)d_in[1];
    const int*   sen_lens = (const int*)d_in[2];
    const float* pos_emb  = (const float*)d_in[3];
    const float* w_ih0    = (const float*)d_in[4];
    const float* w_hh0    = (const float*)d_in[5];
    const float* b_ih0    = (const float*)d_in[6];
    const float* b_hh0    = (const float*)d_in[7];
    const float* w_ih     = (const float*)d_in[8];
    const float* w_hh     = (const float*)d_in[9];
    const float* b_ih     = (const float*)d_in[10];
    const float* b_hh     = (const float*)d_in[11];
    const float* W1       = (const float*)d_in[12];
    const float* b1       = (const float*)d_in[13];
    const float* W2       = (const float*)d_in[14];
    const float* b2       = (const float*)d_in[15];
    const float* W3       = (const float*)d_in[16];
    const float* b3       = (const float*)d_in[17];
    float* out = (float*)d_out;

    // workspace map (dw offsets)
    uint32_t* ws = (uint32_t*)d_ws;
    _Float16* x0hi  = (_Float16*)(ws + 0);          // 128000 dw
    _Float16* x0lo  = (_Float16*)(ws + 128000);     // 128000
    float*    gxf   = (float*)(ws + 256000);        // 3276800  [d][b][tt][1024]
    _Float16* xAhi  = (_Float16*)(ws + 3532800);    // 409600
    _Float16* xAlo  = (_Float16*)(ws + 3942400);    // 409600
    _Float16* xBhi  = (_Float16*)(ws + 5171200);    // 409600
    _Float16* xBlo  = (_Float16*)(ws + 5580800);    // 409600
    float*    hfr   = (float*)(ws + 6809600);       // 1638400
    uint32_t* wihpk = ws + 8448000;                 // 2097152 (8 dl x 262144)
    uint32_t* whhpk = ws + 10545152;                // 1048576 (4 layers x 262144)
    uint32_t* w2pk  = ws + 11593728;                // 65536
    float*    biasp = (float*)(ws + 11659264);      // 8192

    pack_all<<<4168, 256, 0, stream>>>(w_hh0, w_hh, w_ih0, w_ih, W2,
                                       b_ih0, b_hh0, b_ih, b_hh,
                                       we, pos_idx, pos_emb,
                                       whhpk, wihpk, w2pk, biasp, x0hi, x0lo);

    const int LSTM_SMEM = 38016 * 4;   // 152064 B (144K wtail + 4K gbuf + 0.5K h)

    // layer 0 (K = 160 -> KC = 5); both dirs in one launch (grid.z)
    gemm_gx<<<dim3(16, 25, 2), 256, 0, stream>>>(
        x0hi, x0lo, wihpk, biasp, gxf, 5, 160);
    lstm_v9<<<32, 1024, LSTM_SMEM, stream>>>(gxf, whhpk, xAhi, xAlo);

    _Float16* xih = xAhi; _Float16* xil = xAlo;
    _Float16* xoh = xBhi; _Float16* xol = xBlo;
    for (int lyr = 1; lyr < 4; ++lyr) {
        int dlbase = 2 + (lyr - 1) * 2;
        gemm_gx<<<dim3(16, 25, 2), 256, 0, stream>>>(
            xih, xil, wihpk + (size_t)dlbase * 262144,
            biasp + lyr * 2048, gxf, 16, 512);
        lstm_v9<<<32, 1024, LSTM_SMEM, stream>>>(gxf, whhpk + (size_t)lyr * 262144,
                                                 xoh, xol);
        _Float16* th = xih; xih = xoh; xoh = th;
        _Float16* tl = xil; xil = xol; xol = tl;
    }
    // final layer hi/lo in xih/xil (token'-major [t*16+b][512])

    // W1 projections via MFMA; w1pk reuses the (now dead) gxf region
    uint32_t* w1pk = (uint32_t*)gxf;   // 262144 dw needed, 3276800 available
    pack_w1<<<256, 256, 0, stream>>>(W1, w1pk);
    gemm_w1<<<dim3(8, 25, 2), 256, 0, stream>>>(xih, xil, w1pk, hfr);

    zero_pad<<<7, 256, 0, stream>>>(out);
    scorer_v2<<<dim3(7, 13, 16), 256, 0, stream>>>(hfr, w2pk, b1, b2, W3, b3,
                                                   sen_lens, out);
}